// Round 4
// baseline (155.425 us; speedup 1.0000x reference)
//
#include <hip/hip_runtime.h>
#include <hip/hip_bf16.h>

// ---------------------------------------------------------------------------
// DiffusionMemory: temporal conv (3,1,1) + per-frame spatial attention + projs
// C=256, T=16, H*W=1024, heads=8, hd=32.  All matmuls via mfma_f32_16x16x32_bf16.
// ---------------------------------------------------------------------------

typedef __bf16 bf16x8 __attribute__((ext_vector_type(8)));
typedef float  f32x4  __attribute__((ext_vector_type(4)));

__device__ __forceinline__ ushort f2bf(float f) {
    union { float f; unsigned int u; } x; x.f = f;
    unsigned int r = x.u + 0x7FFFu + ((x.u >> 16) & 1u);   // RNE
    return (ushort)(r >> 16);
}

__device__ __forceinline__ ushort f2bf_rtz(float f) {      // truncate (P only)
    union { float f; unsigned int u; } x; x.f = f;
    return (ushort)(x.u >> 16);
}

__device__ __forceinline__ bf16x8 ldg8(const ushort* p) {
    union { int4 i; bf16x8 b; } u;
    u.i = *reinterpret_cast<const int4*>(p);
    return u.b;
}

// ---------------- zero fill (xe_t padding rows) ----------------
__global__ void zero_u4(uint4* p, int n) {
    int i = blockIdx.x * 256 + threadIdx.x;
    if (i < n) p[i] = make_uint4(0u, 0u, 0u, 0u);
}

// ---------------- weight repack to bf16 ----------------
__global__ void prep_weights(const float* __restrict__ qw, const float* __restrict__ kw,
                             const float* __restrict__ vw, const float* __restrict__ ow,
                             const float* __restrict__ tcw,
                             const float* __restrict__ qb, const float* __restrict__ kb,
                             ushort* __restrict__ wqk, ushort* __restrict__ wv,
                             ushort* __restrict__ wo, ushort* __restrict__ wconv,
                             float* __restrict__ bqk)
{
    int i = blockIdx.x * 256 + threadIdx.x;
    if (i < 131072) {                       // wqk
        int m = i >> 8, k = i & 255;
        float val = (m < 256) ? qw[m * 256 + k] : kw[(m - 256) * 256 + k];
        wqk[i] = f2bf(val);
    } else if (i < 196608) {                // wv
        int j = i - 131072;
        wv[j] = f2bf(vw[j]);
    } else if (i < 262144) {                // wo
        int j = i - 196608;
        wo[j] = f2bf(ow[j]);
    } else if (i < 458752) {                // wconv
        int j = i - 262144;
        int o = j / 768, kk = j - o * 768;
        int c = kk & 255, kseg = kk >> 8;
        wconv[j] = f2bf(tcw[o * 768 + c * 3 + kseg]);
    } else if (i < 459264) {                // bqk
        int j = i - 458752;
        bqk[j] = (j < 256) ? qb[j] : kb[j - 256];
    }
}

// ---------------- x transpose ----------------
__global__ __launch_bounds__(256)
void prep_x(const float* __restrict__ x, const float* __restrict__ pos,
            ushort* __restrict__ xpt, ushort* __restrict__ xet)
{
    __shared__ float tile[64][65];
    const int tp0 = blockIdx.x * 64;
    const int c0  = blockIdx.y * 64;
    const int tid = threadIdx.x;

    {
        const int j = tid & 63, i0 = (tid >> 6) * 16;
        #pragma unroll
        for (int rr = 0; rr < 16; ++rr) {
            int i = i0 + rr;
            tile[i][j] = x[(size_t)(c0 + i) * 16384 + tp0 + j];
        }
    }
    __syncthreads();
    {
        const int ii = tid & 63, jj0 = (tid >> 6) * 16;
        #pragma unroll
        for (int rr = 0; rr < 16; ++rr) {
            int jj = jj0 + rr;
            float val = tile[ii][jj];
            int c = c0 + ii, tp = tp0 + jj;
            int t = tp >> 10;
            xpt[(size_t)tp * 256 + c] = f2bf(val + pos[c * 16 + t]);
            xet[(size_t)(tp + 1024) * 256 + c] = f2bf(val);
        }
    }
}

// ---------------- GEMM:  C[m][n] = sum_k A[m][k] * B[n + (k/256)*bshift][k%256] ----------------
// MODE 0: bf16 per-head transposed out (Q/K split)      (Q,K -> qhd/khd)
// MODE 1: bf16 out[m*N + n]                 (+bias)     (V channel-major)
// MODE 2: f32  out[m*N + n]                 (+bias)     (conv local)
// MODE 3: f32  out[m*N + n] + addsrc        (+bias)     (final)
template<int MODE>
__global__ __launch_bounds__(256)
void gemm_bt(const ushort* __restrict__ A, const ushort* __restrict__ B,
             void* __restrict__ outp, const float* __restrict__ bias,
             const float* __restrict__ addsrc,
             const int M, const int N, const int K,
             const int bshift, const int ldout)
{
    __shared__ __align__(16) ushort As[128][72];
    __shared__ __align__(16) ushort Bs[64][72];

    const int tid  = threadIdx.x;
    const int lane = tid & 63;
    const int w    = tid >> 6;
    const int lr   = lane & 15;
    const int hk   = lane >> 4;

    const int n0 = blockIdx.x * 64;
    const int m0 = blockIdx.y * 128;
    const int wm = w * 32;

    const int srow = tid >> 3;
    const int scol = (tid & 7) * 8;

    f32x4 acc[2][4] = {};

    for (int kk0 = 0; kk0 < K; kk0 += 64) {
        const int seg  = kk0 >> 8;
        const int bcol = kk0 & 255;
        __syncthreads();
        #pragma unroll
        for (int q = 0; q < 4; ++q) {
            const int row = srow + q * 32;
            *reinterpret_cast<int4*>(&As[row][scol]) =
                *reinterpret_cast<const int4*>(A + (size_t)(m0 + row) * K + kk0 + scol);
        }
        #pragma unroll
        for (int q = 0; q < 2; ++q) {
            const int row = srow + q * 32;
            *reinterpret_cast<int4*>(&Bs[row][scol]) =
                *reinterpret_cast<const int4*>(B + (size_t)(n0 + row + seg * bshift) * 256 + bcol + scol);
        }
        __syncthreads();
        #pragma unroll
        for (int ks = 0; ks < 2; ++ks) {
            bf16x8 af[2], bfr[4];
            #pragma unroll
            for (int mi = 0; mi < 2; ++mi)
                af[mi] = *reinterpret_cast<const bf16x8*>(&As[wm + mi * 16 + lr][ks * 32 + hk * 8]);
            #pragma unroll
            for (int nj = 0; nj < 4; ++nj)
                bfr[nj] = *reinterpret_cast<const bf16x8*>(&Bs[nj * 16 + lr][ks * 32 + hk * 8]);
            #pragma unroll
            for (int mi = 0; mi < 2; ++mi)
                #pragma unroll
                for (int nj = 0; nj < 4; ++nj)
                    acc[mi][nj] = __builtin_amdgcn_mfma_f32_16x16x32_bf16(af[mi], bfr[nj], acc[mi][nj], 0, 0, 0);
        }
    }

    #pragma unroll
    for (int mi = 0; mi < 2; ++mi) {
        const int mb = m0 + wm + mi * 16 + hk * 4;
        const float b0 = bias[mb + 0], b1 = bias[mb + 1], b2 = bias[mb + 2], b3 = bias[mb + 3];
        #pragma unroll
        for (int nj = 0; nj < 4; ++nj) {
            const int n = n0 + nj * 16 + lr;
            const f32x4 a = acc[mi][nj];
            if constexpr (MODE == 0) {
                ushort4 pk;
                pk.x = f2bf(a[0] + b0); pk.y = f2bf(a[1] + b1);
                pk.z = f2bf(a[2] + b2); pk.w = f2bf(a[3] + b3);
                ushort* o = (ushort*)outp;
                size_t base = (size_t)(mb >> 8) * (8ull * 16384 * 32)
                            + (size_t)((mb >> 5) & 7) * (16384ull * 32)
                            + (mb & 31);
                *reinterpret_cast<ushort4*>(o + base + (size_t)n * 32) = pk;
            } else if constexpr (MODE == 1) {
                ushort* o = (ushort*)outp;
                o[(size_t)(mb + 0) * N + n] = f2bf(a[0] + b0);
                o[(size_t)(mb + 1) * N + n] = f2bf(a[1] + b1);
                o[(size_t)(mb + 2) * N + n] = f2bf(a[2] + b2);
                o[(size_t)(mb + 3) * N + n] = f2bf(a[3] + b3);
            } else if constexpr (MODE == 2) {
                float* o = (float*)outp;
                o[(size_t)(mb + 0) * N + n] = a[0] + b0;
                o[(size_t)(mb + 1) * N + n] = a[1] + b1;
                o[(size_t)(mb + 2) * N + n] = a[2] + b2;
                o[(size_t)(mb + 3) * N + n] = a[3] + b3;
            } else {
                float* o = (float*)outp;
                o[(size_t)(mb + 0) * N + n] = a[0] + b0 + addsrc[(size_t)(mb + 0) * N + n];
                o[(size_t)(mb + 1) * N + n] = a[1] + b1 + addsrc[(size_t)(mb + 1) * N + n];
                o[(size_t)(mb + 2) * N + n] = a[2] + b2 + addsrc[(size_t)(mb + 2) * N + n];
                o[(size_t)(mb + 3) * N + n] = a[3] + b3 + addsrc[(size_t)(mb + 3) * N + n];
            }
        }
    }
}

// ---------------- flash attention over P=1024 per (head, frame) ----------------
// qhd/khd: [8 heads][16384 tp][32 ch] bf16 (dense per-head; contiguous frag loads)
// v      : [256][16384] bf16 (channel-major)
// out    : [16384][256] bf16
// grid (128 problems, 8 qblocks): same-problem blocks land on one XCD.
__global__ __launch_bounds__(256)
void attn_kernel(const ushort* __restrict__ qhd, const ushort* __restrict__ v,
                 ushort* __restrict__ outp)
{
    // P buffer: per wave 32 rows x 64 cols bf16, 16B blocks XOR-swizzled.
    __shared__ __align__(16) ushort P_lds[4][2048];

    const int tid  = threadIdx.x;
    const int lane = tid & 63;
    const int w    = tid >> 6;
    const int lr   = lane & 15;
    const int hk   = lane >> 4;

    const int prob = blockIdx.x;        // 0..127
    const int qb   = blockIdx.y;        // 0..7
    const int hn   = prob >> 4, t = prob & 15;

    const ushort* khd = qhd + 8ull * 16384 * 32;
    const ushort* qh  = qhd + (size_t)hn * 16384 * 32;
    const ushort* kh  = khd + (size_t)hn * 16384 * 32;

    const int p0 = qb * 128 + w * 32;
    const size_t rowbase = (size_t)t * 1024;

    bf16x8 qf[2];
    #pragma unroll
    for (int mi = 0; mi < 2; ++mi)
        qf[mi] = ldg8(qh + (rowbase + p0 + mi * 16 + lr) * 32 + hk * 8);

    union { ushort s[8]; bf16x8 v; } onesu;
    #pragma unroll
    for (int j = 0; j < 8; ++j) onesu.s[j] = 0x3F80;   // bf16 1.0
    const bf16x8 ones = onesu.v;

    f32x4 o_acc[2][2] = {};
    f32x4 lsum[2] = {};
    float mr[2][4];
    #pragma unroll
    for (int mi = 0; mi < 2; ++mi)
        #pragma unroll
        for (int r = 0; r < 4; ++r) mr[mi][r] = -1e30f;

    const float SCL = 0.17677669529663687f * 1.4426950408889634f;  // hd^-0.5 * log2(e)
    const float THR = 3.0f;   // defer-max threshold (log2 domain): P <= 8

    for (int kv0 = 0; kv0 < 1024; kv0 += 64) {
        // ---- S = Q K^T ----
        f32x4 s[2][4] = {};
        #pragma unroll
        for (int nj = 0; nj < 4; ++nj) {
            bf16x8 kf = ldg8(kh + (rowbase + kv0 + nj * 16 + lr) * 32 + hk * 8);
            #pragma unroll
            for (int mi = 0; mi < 2; ++mi)
                s[mi][nj] = __builtin_amdgcn_mfma_f32_16x16x32_bf16(qf[mi], kf, s[mi][nj], 0, 0, 0);
        }
        // ---- issue V loads early (hide under softmax VALU) ----
        bf16x8 vf[2][2];
        #pragma unroll
        for (int kq = 0; kq < 2; ++kq)
            #pragma unroll
            for (int nf = 0; nf < 2; ++nf)
                vf[kq][nf] = ldg8(v + (size_t)(hn * 32 + nf * 16 + lr) * 16384
                                    + rowbase + kv0 + kq * 32 + hk * 8);
        // ---- defer-max check (no reduce in the common case) ----
        float lm[2][4];
        bool grow = false;
        #pragma unroll
        for (int mi = 0; mi < 2; ++mi)
            #pragma unroll
            for (int r = 0; r < 4; ++r) {
                float l4 = fmaxf(fmaxf(s[mi][0][r], s[mi][1][r]),
                                 fmaxf(s[mi][2][r], s[mi][3][r])) * SCL;
                lm[mi][r] = l4;
                grow = grow || (l4 > mr[mi][r] + THR);
            }
        if (__any(grow)) {
            #pragma unroll
            for (int mi = 0; mi < 2; ++mi)
                #pragma unroll
                for (int r = 0; r < 4; ++r) {
                    float nm = lm[mi][r];
                    #pragma unroll
                    for (int off = 1; off < 16; off <<= 1)
                        nm = fmaxf(nm, __shfl_xor(nm, off));
                    float mnew  = fmaxf(mr[mi][r], nm);
                    float alpha = exp2f(mr[mi][r] - mnew);
                    mr[mi][r] = mnew;
                    o_acc[mi][0][r] *= alpha;
                    o_acc[mi][1][r] *= alpha;
                    lsum[mi][r]     *= alpha;
                }
        }
        // ---- P = exp2(s*SCL - mr), store to swizzled LDS (RTZ bf16) ----
        #pragma unroll
        for (int mi = 0; mi < 2; ++mi)
            #pragma unroll
            for (int nj = 0; nj < 4; ++nj)
                #pragma unroll
                for (int r = 0; r < 4; ++r) {
                    float p = exp2f(fmaf(s[mi][nj][r], SCL, -mr[mi][r]));
                    int row = mi * 16 + hk * 4 + r;
                    int col = nj * 16 + lr;
                    int blk = (col >> 3) ^ ((row & 12) >> 1);
                    P_lds[w][row * 64 + blk * 8 + (col & 7)] = f2bf_rtz(p);
                }
        // ---- O += P V ;  lsum += P 1  (MFMA ones-trick) ----
        #pragma unroll
        for (int kq = 0; kq < 2; ++kq) {
            bf16x8 pa[2];
            #pragma unroll
            for (int mi = 0; mi < 2; ++mi) {
                int row = mi * 16 + lr;
                int blk = (kq * 4 + hk) ^ ((lr & 12) >> 1);
                pa[mi] = *reinterpret_cast<const bf16x8*>(&P_lds[w][row * 64 + blk * 8]);
            }
            #pragma unroll
            for (int mi = 0; mi < 2; ++mi)
                lsum[mi] = __builtin_amdgcn_mfma_f32_16x16x32_bf16(pa[mi], ones, lsum[mi], 0, 0, 0);
            #pragma unroll
            for (int nf = 0; nf < 2; ++nf)
                #pragma unroll
                for (int mi = 0; mi < 2; ++mi)
                    o_acc[mi][nf] = __builtin_amdgcn_mfma_f32_16x16x32_bf16(pa[mi], vf[kq][nf], o_acc[mi][nf], 0, 0, 0);
        }
    }

    // ---- epilogue ----
    #pragma unroll
    for (int mi = 0; mi < 2; ++mi) {
        float inv[4];
        #pragma unroll
        for (int r = 0; r < 4; ++r) inv[r] = 1.f / lsum[mi][r];
        #pragma unroll
        for (int nf = 0; nf < 2; ++nf)
            #pragma unroll
            for (int r = 0; r < 4; ++r)
                outp[(rowbase + p0 + mi * 16 + hk * 4 + r) * 256 + hn * 32 + nf * 16 + lr] =
                    f2bf(o_acc[mi][nf][r] * inv[r]);
    }
}

// ---------------------------------------------------------------------------
extern "C" void kernel_launch(void* const* d_in, const int* in_sizes, int n_in,
                              void* d_out, int out_size, void* d_ws, size_t ws_size,
                              hipStream_t stream)
{
    const float* x   = (const float*)d_in[0];
    const float* tcw = (const float*)d_in[1];
    const float* tcb = (const float*)d_in[2];
    const float* qw  = (const float*)d_in[3];
    const float* qb  = (const float*)d_in[4];
    const float* kw  = (const float*)d_in[5];
    const float* kb  = (const float*)d_in[6];
    const float* vw  = (const float*)d_in[7];
    const float* vb  = (const float*)d_in[8];
    const float* ow  = (const float*)d_in[9];
    const float* ob  = (const float*)d_in[10];
    const float* pos = (const float*)d_in[11];

    char* ws = (char*)d_ws;
    size_t off = 0;
    auto alloc = [&](size_t bytes) {
        void* p = ws + off;
        off += (bytes + 255) & ~(size_t)255;
        return p;
    };
    ushort* xpt   = (ushort*)alloc(16384ull * 256 * 2);   // x^T + pos, bf16
    ushort* xet   = (ushort*)alloc(18432ull * 256 * 2);   // x^T zero-padded +-1 frame
    ushort* qkhd  = (ushort*)alloc(2ull * 8 * 16384 * 32 * 2);  // Q then K, per-head dense
    ushort* vbuf  = (ushort*)alloc(256ull * 16384 * 2);   // V channel-major
    ushort* attnb = (ushort*)alloc(16384ull * 256 * 2);   // attention out^T
    float*  local = (float*)alloc(256ull * 16384 * 4);    // conv result f32
    ushort* wqk   = (ushort*)alloc(512ull * 256 * 2);
    ushort* wv    = (ushort*)alloc(256ull * 256 * 2);
    ushort* wo    = (ushort*)alloc(256ull * 256 * 2);
    ushort* wconv = (ushort*)alloc(256ull * 768 * 2);
    float*  bqk   = (float*)alloc(512 * 4);

    zero_u4<<<128, 256, 0, stream>>>((uint4*)xet, 32768);
    zero_u4<<<128, 256, 0, stream>>>((uint4*)(xet + 17408ull * 256), 32768);

    prep_weights<<<1794, 256, 0, stream>>>(qw, kw, vw, ow, tcw, qb, kb, wqk, wv, wo, wconv, bqk);
    prep_x<<<dim3(256, 4), 256, 0, stream>>>(x, pos, xpt, xet);

    // Q,K fused (M=512) -> per-head dense layout
    gemm_bt<0><<<dim3(256, 4), 256, 0, stream>>>(wqk, xpt, qkhd, bqk, nullptr, 512, 16384, 256, 0, 0);
    // V -> channel-major bf16
    gemm_bt<1><<<dim3(256, 2), 256, 0, stream>>>(wv, xpt, vbuf, vb, nullptr, 256, 16384, 256, 0, 0);
    // temporal conv as K=768 GEMM over shifted x^T
    gemm_bt<2><<<dim3(256, 2), 256, 0, stream>>>(wconv, xet, local, tcb, nullptr, 256, 16384, 768, 1024, 0);

    attn_kernel<<<dim3(128, 8), 256, 0, stream>>>(qkhd, vbuf, attnb);

    // final: o-proj + local + bias -> d_out (f32)
    gemm_bt<3><<<dim3(256, 2), 256, 0, stream>>>(wo, attnb, (float*)d_out, ob, local, 256, 16384, 256, 0, 0);
}

// Round 5
// 133.456 us; speedup vs baseline: 1.1646x; 1.1646x over previous
//
#include <hip/hip_runtime.h>
#include <hip/hip_bf16.h>

// ---------------------------------------------------------------------------
// DiffusionMemory: temporal conv (3,1,1) + per-frame spatial attention + projs
// C=256, T=16, H*W=1024, heads=8, hd=32.  All matmuls via mfma_f32_16x16x32_bf16.
// Attention: swapped QK^T (T12) -> P lane-local per q-row; P re-fragmentation
// for PV via cvt_pk_bf16 + permlane16/32_swap (zero LDS in attention).
// ---------------------------------------------------------------------------

typedef __bf16 bf16x8 __attribute__((ext_vector_type(8)));
typedef float  f32x4  __attribute__((ext_vector_type(4)));

__device__ __forceinline__ ushort f2bf(float f) {
    union { float f; unsigned int u; } x; x.f = f;
    unsigned int r = x.u + 0x7FFFu + ((x.u >> 16) & 1u);   // RNE
    return (ushort)(r >> 16);
}

__device__ __forceinline__ float bf2f(ushort u) {
    union { unsigned int i; float f; } x; x.i = (unsigned int)u << 16;
    return x.f;
}

__device__ __forceinline__ bf16x8 ldg8(const ushort* p) {
    union { int4 i; bf16x8 b; } u;
    u.i = *reinterpret_cast<const int4*>(p);
    return u.b;
}

// ---------------- zero fill: both xe_t padding frame regions in one launch ----
__global__ void zero_pad(uint4* a, uint4* b) {
    int i = blockIdx.x * 256 + threadIdx.x;
    if (i < 32768) { a[i] = make_uint4(0u,0u,0u,0u); b[i] = make_uint4(0u,0u,0u,0u); }
}

// ---------------- weight repack to bf16 ----------------
// wqkv [768][256] (Q,K,V rows), wo [256][256], wconv [256][768] col=k*256+c,
// bqkv [768] = concat(q_b, k_b, v_b)
__global__ void prep_weights(const float* __restrict__ qw, const float* __restrict__ kw,
                             const float* __restrict__ vw, const float* __restrict__ ow,
                             const float* __restrict__ tcw,
                             const float* __restrict__ qb, const float* __restrict__ kb,
                             const float* __restrict__ vb,
                             ushort* __restrict__ wqkv, ushort* __restrict__ wo,
                             ushort* __restrict__ wconv, float* __restrict__ bqkv)
{
    int i = blockIdx.x * 256 + threadIdx.x;
    if (i < 196608) {                        // wqkv
        int m = i >> 8, k = i & 255;
        float val = (m < 256) ? qw[m * 256 + k]
                  : (m < 512) ? kw[(m - 256) * 256 + k]
                              : vw[(m - 512) * 256 + k];
        wqkv[i] = f2bf(val);
    } else if (i < 262144) {                 // wo
        int j = i - 196608;
        wo[j] = f2bf(ow[j]);
    } else if (i < 458752) {                 // wconv
        int j = i - 262144;
        int o = j / 768, kk = j - o * 768;
        int c = kk & 255, kseg = kk >> 8;
        wconv[j] = f2bf(tcw[o * 768 + c * 3 + kseg]);
    } else if (i < 459520) {                 // bqkv
        int j = i - 458752;
        bqkv[j] = (j < 256) ? qb[j] : (j < 512) ? kb[j - 256] : vb[j - 512];
    }
}

// ---------------- x transpose ----------------
__global__ __launch_bounds__(256)
void prep_x(const float* __restrict__ x, const float* __restrict__ pos,
            ushort* __restrict__ xpt, ushort* __restrict__ xet)
{
    __shared__ float tile[64][65];
    const int tp0 = blockIdx.x * 64;
    const int c0  = blockIdx.y * 64;
    const int tid = threadIdx.x;

    {
        const int j = tid & 63, i0 = (tid >> 6) * 16;
        #pragma unroll
        for (int rr = 0; rr < 16; ++rr) {
            int i = i0 + rr;
            tile[i][j] = x[(size_t)(c0 + i) * 16384 + tp0 + j];
        }
    }
    __syncthreads();
    {
        const int ii = tid & 63, jj0 = (tid >> 6) * 16;
        #pragma unroll
        for (int rr = 0; rr < 16; ++rr) {
            int jj = jj0 + rr;
            float val = tile[ii][jj];
            int c = c0 + ii, tp = tp0 + jj;
            int t = tp >> 10;
            xpt[(size_t)tp * 256 + c] = f2bf(val + pos[c * 16 + t]);
            xet[(size_t)(tp + 1024) * 256 + c] = f2bf(val);
        }
    }
}

// ---------------- GEMM:  C[m][n] = sum_k A[m][k] * B[n + (k/256)*bshift][k%256] ----
// MODE 0: rows<512 -> qkhd per-head layout; rows>=512 -> vbuf channel-major (outp2)
// MODE 2: bf16 out[m*N + n]                (+bias)     (conv local)
// MODE 3: f32  out[m*N + n] + bf16 addsrc  (+bias)     (final)
template<int MODE>
__global__ __launch_bounds__(256)
void gemm_bt(const ushort* __restrict__ A, const ushort* __restrict__ B,
             void* __restrict__ outp, void* __restrict__ outp2,
             const float* __restrict__ bias, const ushort* __restrict__ addsrc,
             const int M, const int N, const int K, const int bshift)
{
    __shared__ __align__(16) ushort As[128][72];
    __shared__ __align__(16) ushort Bs[64][72];

    const int tid  = threadIdx.x;
    const int lane = tid & 63;
    const int w    = tid >> 6;
    const int lr   = lane & 15;
    const int hk   = lane >> 4;

    const int n0 = blockIdx.x * 64;
    const int m0 = blockIdx.y * 128;
    const int wm = w * 32;

    const int srow = tid >> 3;
    const int scol = (tid & 7) * 8;

    f32x4 acc[2][4] = {};

    for (int kk0 = 0; kk0 < K; kk0 += 64) {
        const int seg  = kk0 >> 8;
        const int bcol = kk0 & 255;
        __syncthreads();
        #pragma unroll
        for (int q = 0; q < 4; ++q) {
            const int row = srow + q * 32;
            *reinterpret_cast<int4*>(&As[row][scol]) =
                *reinterpret_cast<const int4*>(A + (size_t)(m0 + row) * K + kk0 + scol);
        }
        #pragma unroll
        for (int q = 0; q < 2; ++q) {
            const int row = srow + q * 32;
            *reinterpret_cast<int4*>(&Bs[row][scol]) =
                *reinterpret_cast<const int4*>(B + (size_t)(n0 + row + seg * bshift) * 256 + bcol + scol);
        }
        __syncthreads();
        #pragma unroll
        for (int ks = 0; ks < 2; ++ks) {
            bf16x8 af[2], bfr[4];
            #pragma unroll
            for (int mi = 0; mi < 2; ++mi)
                af[mi] = *reinterpret_cast<const bf16x8*>(&As[wm + mi * 16 + lr][ks * 32 + hk * 8]);
            #pragma unroll
            for (int nj = 0; nj < 4; ++nj)
                bfr[nj] = *reinterpret_cast<const bf16x8*>(&Bs[nj * 16 + lr][ks * 32 + hk * 8]);
            #pragma unroll
            for (int mi = 0; mi < 2; ++mi)
                #pragma unroll
                for (int nj = 0; nj < 4; ++nj)
                    acc[mi][nj] = __builtin_amdgcn_mfma_f32_16x16x32_bf16(af[mi], bfr[nj], acc[mi][nj], 0, 0, 0);
        }
    }

    #pragma unroll
    for (int mi = 0; mi < 2; ++mi) {
        const int mb = m0 + wm + mi * 16 + hk * 4;
        const float b0 = bias[mb + 0], b1 = bias[mb + 1], b2 = bias[mb + 2], b3 = bias[mb + 3];
        #pragma unroll
        for (int nj = 0; nj < 4; ++nj) {
            const int n = n0 + nj * 16 + lr;
            const f32x4 a = acc[mi][nj];
            if constexpr (MODE == 0) {
                if (mb < 512) {                  // Q,K -> per-head dense layout
                    ushort4 pk;
                    pk.x = f2bf(a[0] + b0); pk.y = f2bf(a[1] + b1);
                    pk.z = f2bf(a[2] + b2); pk.w = f2bf(a[3] + b3);
                    ushort* o = (ushort*)outp;
                    size_t base = (size_t)(mb >> 8) * (8ull * 16384 * 32)
                                + (size_t)((mb >> 5) & 7) * (16384ull * 32)
                                + (mb & 31);
                    *reinterpret_cast<ushort4*>(o + base + (size_t)n * 32) = pk;
                } else {                         // V -> channel-major
                    int c = mb - 512;
                    ushort* o = (ushort*)outp2;
                    o[(size_t)(c + 0) * 16384 + n] = f2bf(a[0] + b0);
                    o[(size_t)(c + 1) * 16384 + n] = f2bf(a[1] + b1);
                    o[(size_t)(c + 2) * 16384 + n] = f2bf(a[2] + b2);
                    o[(size_t)(c + 3) * 16384 + n] = f2bf(a[3] + b3);
                }
            } else if constexpr (MODE == 2) {
                ushort* o = (ushort*)outp;
                o[(size_t)(mb + 0) * N + n] = f2bf(a[0] + b0);
                o[(size_t)(mb + 1) * N + n] = f2bf(a[1] + b1);
                o[(size_t)(mb + 2) * N + n] = f2bf(a[2] + b2);
                o[(size_t)(mb + 3) * N + n] = f2bf(a[3] + b3);
            } else {
                float* o = (float*)outp;
                o[(size_t)(mb + 0) * N + n] = a[0] + b0 + bf2f(addsrc[(size_t)(mb + 0) * N + n]);
                o[(size_t)(mb + 1) * N + n] = a[1] + b1 + bf2f(addsrc[(size_t)(mb + 1) * N + n]);
                o[(size_t)(mb + 2) * N + n] = a[2] + b2 + bf2f(addsrc[(size_t)(mb + 2) * N + n]);
                o[(size_t)(mb + 3) * N + n] = a[3] + b3 + bf2f(addsrc[(size_t)(mb + 3) * N + n]);
            }
        }
    }
}

// ---------------- flash attention, zero-LDS (swapped QK^T + permlane) --------
// qhd: [2(q,k)][8 heads][16384 tp][32 ch] bf16
// v  : [256][16384] bf16 (channel-major)
// out: [16384][256] bf16
__global__ __launch_bounds__(256, 4)
void attn_kernel(const ushort* __restrict__ qhd, const ushort* __restrict__ v,
                 ushort* __restrict__ outp)
{
    const int lane = threadIdx.x & 63;
    const int w    = threadIdx.x >> 6;
    const int lr   = lane & 15;
    const int hk   = lane >> 4;

    const int prob = blockIdx.x;        // 0..127  (head*16 + t)
    const int qb   = blockIdx.y;        // 0..7
    const int hn   = prob >> 4, t = prob & 15;

    const ushort* qh = qhd + (size_t)hn * (16384 * 32);
    const ushort* kh = qhd + 8ull * 16384 * 32 + (size_t)hn * (16384 * 32);

    const int p0 = qb * 128 + w * 32;
    const size_t rowbase = (size_t)t * 1024;

    // Q fragments (B-operand of swapped QK^T): lane holds Q[p0+mi*16+lr][hk*8..]
    bf16x8 qf[2];
    #pragma unroll
    for (int mi = 0; mi < 2; ++mi)
        qf[mi] = ldg8(qh + (rowbase + p0 + mi * 16 + lr) * 32 + hk * 8);

    union { ushort s[8]; bf16x8 v; } onesu;
    #pragma unroll
    for (int j = 0; j < 8; ++j) onesu.s[j] = 0x3F80;   // bf16 1.0
    const bf16x8 ones = onesu.v;

    f32x4 o_acc[2][2] = {};
    f32x4 lsum[2] = {};            // row-sum in o_acc layout (q = hk*4+r)
    float mr[2] = {-1e30f, -1e30f};  // running max, q = lr (per mi)

    const float SCL = 0.17677669529663687f * 1.4426950408889634f;  // hd^-0.5 * log2(e)
    const float THR = 3.0f;

    for (int kv0 = 0; kv0 < 1024; kv0 += 64) {
        // ---- V loads first (hide HBM/L2 latency under QK^T + softmax) ----
        bf16x8 vf[2][2];
        #pragma unroll
        for (int kq = 0; kq < 2; ++kq)
            #pragma unroll
            for (int nf = 0; nf < 2; ++nf)
                vf[kq][nf] = ldg8(v + (size_t)(hn * 32 + nf * 16 + lr) * 16384
                                    + rowbase + kv0 + kq * 32 + hk * 8);
        // ---- S^T = K Q^T : lane holds S[q=lr][k = nj*16 + hk*4 + r] ----
        f32x4 s[4][2] = {};
        #pragma unroll
        for (int nj = 0; nj < 4; ++nj) {
            bf16x8 kf = ldg8(kh + (rowbase + kv0 + nj * 16 + lr) * 32 + hk * 8);
            #pragma unroll
            for (int mi = 0; mi < 2; ++mi)
                s[nj][mi] = __builtin_amdgcn_mfma_f32_16x16x32_bf16(kf, qf[mi], s[nj][mi], 0, 0, 0);
        }
        // ---- defer-max: lane-local 16-max per mi ----
        float lm[2];
        #pragma unroll
        for (int mi = 0; mi < 2; ++mi) {
            float a = fmaxf(fmaxf(s[0][mi][0], s[0][mi][1]), fmaxf(s[0][mi][2], s[0][mi][3]));
            float b = fmaxf(fmaxf(s[1][mi][0], s[1][mi][1]), fmaxf(s[1][mi][2], s[1][mi][3]));
            float c = fmaxf(fmaxf(s[2][mi][0], s[2][mi][1]), fmaxf(s[2][mi][2], s[2][mi][3]));
            float d = fmaxf(fmaxf(s[3][mi][0], s[3][mi][1]), fmaxf(s[3][mi][2], s[3][mi][3]));
            lm[mi] = fmaxf(fmaxf(a, b), fmaxf(c, d)) * SCL;
        }
        bool grow = (lm[0] > mr[0] + THR) || (lm[1] > mr[1] + THR);
        if (__any(grow)) {
            #pragma unroll
            for (int mi = 0; mi < 2; ++mi) {
                float nm = lm[mi];
                nm = fmaxf(nm, __shfl_xor(nm, 16));
                nm = fmaxf(nm, __shfl_xor(nm, 32));     // reduce over hk-groups (same q)
                float mnew  = fmaxf(mr[mi], nm);
                float alpha = exp2f(mr[mi] - mnew);     // keyed q = lr
                mr[mi] = mnew;
                #pragma unroll
                for (int r = 0; r < 4; ++r) {
                    float ar = __shfl(alpha, hk * 4 + r, 16);   // rekey to q = hk*4+r
                    o_acc[mi][0][r] *= ar;
                    o_acc[mi][1][r] *= ar;
                    lsum[mi][r]     *= ar;
                }
            }
        }
        // ---- P = exp2(s*SCL - mr); pack; permlane re-fragmentation ----
        uint u[2][8];
        #pragma unroll
        for (int mi = 0; mi < 2; ++mi) {
            float ps[16];
            #pragma unroll
            for (int nj = 0; nj < 4; ++nj)
                #pragma unroll
                for (int r = 0; r < 4; ++r)
                    ps[nj * 4 + r] = exp2f(fmaf(s[nj][mi][r], SCL, -mr[mi]));
            #pragma unroll
            for (int j = 0; j < 8; ++j)
                asm("v_cvt_pk_bf16_f32 %0, %1, %2" : "=v"(u[mi][j]) : "v"(ps[2 * j]), "v"(ps[2 * j + 1]));
            // quads held: {hk, 4+hk, 8+hk, 12+hk}; needed: {2hk, 2hk+1, 8+2hk, 8+2hk+1}
            asm("v_permlane32_swap_b32 %0, %1" : "+v"(u[mi][0]), "+v"(u[mi][2]));
            asm("v_permlane32_swap_b32 %0, %1" : "+v"(u[mi][1]), "+v"(u[mi][3]));
            asm("v_permlane16_swap_b32 %0, %1" : "+v"(u[mi][0]), "+v"(u[mi][2]));
            asm("v_permlane16_swap_b32 %0, %1" : "+v"(u[mi][1]), "+v"(u[mi][3]));
            asm("v_permlane32_swap_b32 %0, %1" : "+v"(u[mi][4]), "+v"(u[mi][6]));
            asm("v_permlane32_swap_b32 %0, %1" : "+v"(u[mi][5]), "+v"(u[mi][7]));
            asm("v_permlane16_swap_b32 %0, %1" : "+v"(u[mi][4]), "+v"(u[mi][6]));
            asm("v_permlane16_swap_b32 %0, %1" : "+v"(u[mi][5]), "+v"(u[mi][7]));
        }
        // ---- O += P V ;  lsum += P 1 ----
        #pragma unroll
        for (int kq = 0; kq < 2; ++kq) {
            #pragma unroll
            for (int mi = 0; mi < 2; ++mi) {
                union { uint4 i; bf16x8 b; } pu;
                pu.i = make_uint4(u[mi][kq * 4 + 0], u[mi][kq * 4 + 1],
                                  u[mi][kq * 4 + 2], u[mi][kq * 4 + 3]);
                lsum[mi] = __builtin_amdgcn_mfma_f32_16x16x32_bf16(pu.b, ones, lsum[mi], 0, 0, 0);
                #pragma unroll
                for (int nf = 0; nf < 2; ++nf)
                    o_acc[mi][nf] = __builtin_amdgcn_mfma_f32_16x16x32_bf16(pu.b, vf[kq][nf], o_acc[mi][nf], 0, 0, 0);
            }
        }
    }

    // ---- epilogue: lsum already in o_acc layout ----
    #pragma unroll
    for (int mi = 0; mi < 2; ++mi) {
        float inv[4];
        #pragma unroll
        for (int r = 0; r < 4; ++r) inv[r] = 1.f / lsum[mi][r];
        #pragma unroll
        for (int nf = 0; nf < 2; ++nf)
            #pragma unroll
            for (int r = 0; r < 4; ++r)
                outp[(rowbase + p0 + mi * 16 + hk * 4 + r) * 256 + hn * 32 + nf * 16 + lr] =
                    f2bf(o_acc[mi][nf][r] * inv[r]);
    }
}

// ---------------------------------------------------------------------------
extern "C" void kernel_launch(void* const* d_in, const int* in_sizes, int n_in,
                              void* d_out, int out_size, void* d_ws, size_t ws_size,
                              hipStream_t stream)
{
    const float* x   = (const float*)d_in[0];
    const float* tcw = (const float*)d_in[1];
    const float* tcb = (const float*)d_in[2];
    const float* qw  = (const float*)d_in[3];
    const float* qb  = (const float*)d_in[4];
    const float* kw  = (const float*)d_in[5];
    const float* kb  = (const float*)d_in[6];
    const float* vw  = (const float*)d_in[7];
    const float* vb  = (const float*)d_in[8];
    const float* ow  = (const float*)d_in[9];
    const float* ob  = (const float*)d_in[10];
    const float* pos = (const float*)d_in[11];

    char* ws = (char*)d_ws;
    size_t off = 0;
    auto alloc = [&](size_t bytes) {
        void* p = ws + off;
        off += (bytes + 255) & ~(size_t)255;
        return p;
    };
    ushort* xpt    = (ushort*)alloc(16384ull * 256 * 2);        // x^T + pos
    ushort* xet    = (ushort*)alloc(18432ull * 256 * 2);        // x^T zero-padded
    ushort* qkhd   = (ushort*)alloc(2ull * 8 * 16384 * 32 * 2); // Q,K per-head dense
    ushort* vbuf   = (ushort*)alloc(256ull * 16384 * 2);        // V channel-major
    ushort* attnb  = (ushort*)alloc(16384ull * 256 * 2);        // attention out^T
    ushort* localb = (ushort*)alloc(256ull * 16384 * 2);        // conv result bf16
    ushort* wqkv   = (ushort*)alloc(768ull * 256 * 2);
    ushort* wo     = (ushort*)alloc(256ull * 256 * 2);
    ushort* wconv  = (ushort*)alloc(256ull * 768 * 2);
    float*  bqkv   = (float*)alloc(768 * 4);

    zero_pad<<<128, 256, 0, stream>>>((uint4*)xet, (uint4*)(xet + 17408ull * 256));
    prep_weights<<<1795, 256, 0, stream>>>(qw, kw, vw, ow, tcw, qb, kb, vb,
                                           wqkv, wo, wconv, bqkv);
    prep_x<<<dim3(256, 4), 256, 0, stream>>>(x, pos, xpt, xet);

    // fused Q,K,V projection (M=768): Q,K -> qkhd; V -> vbuf
    gemm_bt<0><<<dim3(256, 6), 256, 0, stream>>>(wqkv, xpt, qkhd, vbuf, bqkv, nullptr,
                                                 768, 16384, 256, 0);
    // temporal conv as K=768 GEMM over shifted x^T -> bf16 local
    gemm_bt<2><<<dim3(256, 2), 256, 0, stream>>>(wconv, xet, localb, nullptr, tcb, nullptr,
                                                 256, 16384, 768, 1024);

    attn_kernel<<<dim3(128, 8), 256, 0, stream>>>(qkhd, vbuf, attnb);

    // final: o-proj + local + bias -> d_out (f32)
    gemm_bt<3><<<dim3(256, 2), 256, 0, stream>>>(wo, attnb, (float*)d_out, nullptr, ob, localb,
                                                 256, 16384, 256, 0);
}

// Round 6
// 111.946 us; speedup vs baseline: 1.3884x; 1.1921x over previous
//
#include <hip/hip_runtime.h>
#include <hip/hip_bf16.h>

// ---------------------------------------------------------------------------
// DiffusionMemory: temporal conv (3,1,1) + per-frame spatial attention + projs
// C=256, T=16, H*W=1024, heads=8, hd=32.  All matmuls via mfma_f32_16x16x32_bf16.
// Attention: swapped QK^T -> P lane-local; re-fragmentation via cvt_pk+permlane
// (zero LDS).  Softmax scale folded into Q at projection time.
// Final GEMM fuses o-proj (K=256 on attnb) + temporal conv (K=768 on xet).
// ---------------------------------------------------------------------------

typedef __bf16 bf16x8 __attribute__((ext_vector_type(8)));
typedef float  f32x4  __attribute__((ext_vector_type(4)));

__device__ __forceinline__ ushort f2bf(float f) {
    union { float f; unsigned int u; } x; x.f = f;
    unsigned int r = x.u + 0x7FFFu + ((x.u >> 16) & 1u);   // RNE
    return (ushort)(r >> 16);
}

__device__ __forceinline__ bf16x8 ldg8(const ushort* p) {
    union { int4 i; bf16x8 b; } u;
    u.i = *reinterpret_cast<const int4*>(p);
    return u.b;
}

#define SCL_QK 0.25504600765996234f   // hd^-0.5 * log2(e)

// ---------------- misc prep: pad zeroing + weight repack (one launch) --------
// wqkv [768][256] (Q,K,V rows; Q rows pre-scaled later in GEMM epilogue),
// wfin [256][1024] = [wo | wconv(col=256+kseg*256+c)], bqkv[768], bfin[256]=ob+tcb
__global__ void prep_misc(const float* __restrict__ qw, const float* __restrict__ kw,
                          const float* __restrict__ vw, const float* __restrict__ ow,
                          const float* __restrict__ tcw,
                          const float* __restrict__ qb, const float* __restrict__ kb,
                          const float* __restrict__ vb, const float* __restrict__ ob,
                          const float* __restrict__ tcb,
                          ushort* __restrict__ wqkv, ushort* __restrict__ wfin,
                          float* __restrict__ bqkv, float* __restrict__ bfin,
                          uint4* __restrict__ pad0, uint4* __restrict__ pad1)
{
    int i = blockIdx.x * 256 + threadIdx.x;
    if (i < 65536) {                         // zero xet padding frames
        if (i < 32768) pad0[i] = make_uint4(0u,0u,0u,0u);
        else           pad1[i - 32768] = make_uint4(0u,0u,0u,0u);
        return;
    }
    int j = i - 65536;
    if (j < 196608) {                        // wqkv
        int m = j >> 8, k = j & 255;
        float val = (m < 256) ? qw[m * 256 + k]
                  : (m < 512) ? kw[(m - 256) * 256 + k]
                              : vw[(m - 512) * 256 + k];
        wqkv[j] = f2bf(val);
    } else if (j < 458752) {                 // wfin [256][1024]
        int p = j - 196608;
        int o = p >> 10, col = p & 1023;
        float val;
        if (col < 256) val = ow[o * 256 + col];
        else { int q = col - 256; int c = q & 255, kseg = q >> 8;
               val = tcw[o * 768 + c * 3 + kseg]; }
        wfin[p] = f2bf(val);
    } else if (j < 459520) {                 // bqkv
        int b = j - 458752;
        bqkv[b] = (b < 256) ? qb[b] : (b < 512) ? kb[b - 256] : vb[b - 512];
    } else if (j < 459776) {                 // bfin = ob + tcb
        int b = j - 459520;
        bfin[b] = ob[b] + tcb[b];
    }
}

// ---------------- x transpose ----------------
__global__ __launch_bounds__(256)
void prep_x(const float* __restrict__ x, const float* __restrict__ pos,
            ushort* __restrict__ xpt, ushort* __restrict__ xet)
{
    __shared__ float tile[64][65];
    const int tp0 = blockIdx.x * 64;
    const int c0  = blockIdx.y * 64;
    const int tid = threadIdx.x;

    {
        const int j = tid & 63, i0 = (tid >> 6) * 16;
        #pragma unroll
        for (int rr = 0; rr < 16; ++rr) {
            int i = i0 + rr;
            tile[i][j] = x[(size_t)(c0 + i) * 16384 + tp0 + j];
        }
    }
    __syncthreads();
    {
        const int ii = tid & 63, jj0 = (tid >> 6) * 16;
        #pragma unroll
        for (int rr = 0; rr < 16; ++rr) {
            int jj = jj0 + rr;
            float val = tile[ii][jj];
            int c = c0 + ii, tp = tp0 + jj;
            int t = tp >> 10;
            xpt[(size_t)tp * 256 + c] = f2bf(val + pos[c * 16 + t]);
            xet[(size_t)(tp + 1024) * 256 + c] = f2bf(val);
        }
    }
}

// ---------------- GEMM:  C[m][n] = sum_k A[m][k] * B'[.,k%256] ----------------
// MODE 0: QKV projection, K=256. rows<256: Q (scaled by SCL_QK) -> qkhd;
//         rows<512: K -> qkhd; rows>=512: V channel-major -> outp2.
// MODE 3: fused final, K=1024. seg0: B=attnb rows n; seg1-3: B2=xet rows
//         n+(seg-1)*1024.  f32 out + bias (= ob+tcb).
template<int MODE>
__global__ __launch_bounds__(256)
void gemm_bt(const ushort* __restrict__ A, const ushort* __restrict__ B,
             const ushort* __restrict__ B2,
             void* __restrict__ outp, void* __restrict__ outp2,
             const float* __restrict__ bias,
             const int M, const int N, const int K)
{
    __shared__ __align__(16) ushort As[128][72];
    __shared__ __align__(16) ushort Bs[64][72];

    const int tid  = threadIdx.x;
    const int lane = tid & 63;
    const int w    = tid >> 6;
    const int lr   = lane & 15;
    const int hk   = lane >> 4;

    const int n0 = blockIdx.x * 64;
    const int m0 = blockIdx.y * 128;
    const int wm = w * 32;

    const int srow = tid >> 3;
    const int scol = (tid & 7) * 8;

    f32x4 acc[2][4] = {};

    for (int kk0 = 0; kk0 < K; kk0 += 64) {
        const int seg  = kk0 >> 8;
        const int bcol = kk0 & 255;
        const ushort* bs;
        if constexpr (MODE == 3)
            bs = (seg == 0) ? B : B2 + ((size_t)(seg - 1) << 18);   // +(seg-1)*1024*256
        else
            bs = B;
        __syncthreads();
        #pragma unroll
        for (int q = 0; q < 4; ++q) {
            const int row = srow + q * 32;
            *reinterpret_cast<int4*>(&As[row][scol]) =
                *reinterpret_cast<const int4*>(A + (size_t)(m0 + row) * K + kk0 + scol);
        }
        #pragma unroll
        for (int q = 0; q < 2; ++q) {
            const int row = srow + q * 32;
            *reinterpret_cast<int4*>(&Bs[row][scol]) =
                *reinterpret_cast<const int4*>(bs + (size_t)(n0 + row) * 256 + bcol + scol);
        }
        __syncthreads();
        #pragma unroll
        for (int ks = 0; ks < 2; ++ks) {
            bf16x8 af[2], bfr[4];
            #pragma unroll
            for (int mi = 0; mi < 2; ++mi)
                af[mi] = *reinterpret_cast<const bf16x8*>(&As[wm + mi * 16 + lr][ks * 32 + hk * 8]);
            #pragma unroll
            for (int nj = 0; nj < 4; ++nj)
                bfr[nj] = *reinterpret_cast<const bf16x8*>(&Bs[nj * 16 + lr][ks * 32 + hk * 8]);
            #pragma unroll
            for (int mi = 0; mi < 2; ++mi)
                #pragma unroll
                for (int nj = 0; nj < 4; ++nj)
                    acc[mi][nj] = __builtin_amdgcn_mfma_f32_16x16x32_bf16(af[mi], bfr[nj], acc[mi][nj], 0, 0, 0);
        }
    }

    #pragma unroll
    for (int mi = 0; mi < 2; ++mi) {
        const int mb = m0 + wm + mi * 16 + hk * 4;
        const float b0 = bias[mb + 0], b1 = bias[mb + 1], b2 = bias[mb + 2], b3 = bias[mb + 3];
        #pragma unroll
        for (int nj = 0; nj < 4; ++nj) {
            const int n = n0 + nj * 16 + lr;
            const f32x4 a = acc[mi][nj];
            if constexpr (MODE == 0) {
                if (mb < 512) {                  // Q (scaled), K -> per-head dense
                    const float sc = (mb < 256) ? SCL_QK : 1.0f;
                    ushort4 pk;
                    pk.x = f2bf((a[0] + b0) * sc); pk.y = f2bf((a[1] + b1) * sc);
                    pk.z = f2bf((a[2] + b2) * sc); pk.w = f2bf((a[3] + b3) * sc);
                    ushort* o = (ushort*)outp;
                    size_t base = (size_t)(mb >> 8) * (8ull * 16384 * 32)
                                + (size_t)((mb >> 5) & 7) * (16384ull * 32)
                                + (mb & 31);
                    *reinterpret_cast<ushort4*>(o + base + (size_t)n * 32) = pk;
                } else {                         // V -> channel-major
                    int c = mb - 512;
                    ushort* o = (ushort*)outp2;
                    o[(size_t)(c + 0) * 16384 + n] = f2bf(a[0] + b0);
                    o[(size_t)(c + 1) * 16384 + n] = f2bf(a[1] + b1);
                    o[(size_t)(c + 2) * 16384 + n] = f2bf(a[2] + b2);
                    o[(size_t)(c + 3) * 16384 + n] = f2bf(a[3] + b3);
                }
            } else {
                float* o = (float*)outp;
                o[(size_t)(mb + 0) * N + n] = a[0] + b0;
                o[(size_t)(mb + 1) * N + n] = a[1] + b1;
                o[(size_t)(mb + 2) * N + n] = a[2] + b2;
                o[(size_t)(mb + 3) * N + n] = a[3] + b3;
            }
        }
    }
}

// ---------------- flash attention, zero-LDS (swapped QK^T + permlane) --------
// qhd: [2(q,k)][8 heads][16384 tp][32 ch] bf16 (Q pre-scaled by SCL_QK)
// v  : [256][16384] bf16 (channel-major)
// out: [16384][256] bf16
__global__ __launch_bounds__(256)
void attn_kernel(const ushort* __restrict__ qhd, const ushort* __restrict__ v,
                 ushort* __restrict__ outp)
{
    const int lane = threadIdx.x & 63;
    const int w    = threadIdx.x >> 6;
    const int lr   = lane & 15;
    const int hk   = lane >> 4;

    const int prob = blockIdx.x;        // 0..127  (head*16 + t)
    const int qb   = blockIdx.y;        // 0..7
    const int hn   = prob >> 4, t = prob & 15;

    const ushort* qh = qhd + (size_t)hn * (16384 * 32);
    const ushort* kh = qhd + 8ull * 16384 * 32 + (size_t)hn * (16384 * 32);

    const int p0 = qb * 128 + w * 32;
    const size_t rowbase = (size_t)t * 1024;

    // hoisted per-lane base pointers
    const ushort* kbase = kh + (rowbase + lr) * 32 + hk * 8;              // + (kv0+nj*16)*32
    const ushort* vbase = v + (size_t)(hn * 32 + lr) * 16384 + rowbase + hk * 8;  // + nf*262144 + kv0 + kq*32

    // Q fragments (B-operand of swapped QK^T)
    bf16x8 qf[2];
    #pragma unroll
    for (int mi = 0; mi < 2; ++mi)
        qf[mi] = ldg8(qh + (rowbase + p0 + mi * 16 + lr) * 32 + hk * 8);

    union { ushort s[8]; bf16x8 v; } onesu;
    #pragma unroll
    for (int j = 0; j < 8; ++j) onesu.s[j] = 0x3F80;   // bf16 1.0
    const bf16x8 ones = onesu.v;

    f32x4 o_acc[2][2] = {};
    f32x4 lsum[2] = {};              // row-sum in o_acc layout (q = hk*4+r)
    float mr[2] = {-1e30f, -1e30f};  // running max (log2 domain), q = lr

    const float THR = 3.0f;

    for (int kv0 = 0; kv0 < 1024; kv0 += 64) {
        // ---- V loads first (hide latency under QK^T + softmax) ----
        bf16x8 vf[2][2];
        #pragma unroll
        for (int kq = 0; kq < 2; ++kq)
            #pragma unroll
            for (int nf = 0; nf < 2; ++nf)
                vf[kq][nf] = ldg8(vbase + (size_t)nf * 262144 + kv0 + kq * 32);
        // ---- K loads, then MFMA cluster ----
        bf16x8 kf[4];
        #pragma unroll
        for (int nj = 0; nj < 4; ++nj)
            kf[nj] = ldg8(kbase + (size_t)(kv0 + nj * 16) * 32);
        f32x4 s[4][2] = {};
        __builtin_amdgcn_s_setprio(1);
        #pragma unroll
        for (int nj = 0; nj < 4; ++nj)
            #pragma unroll
            for (int mi = 0; mi < 2; ++mi)
                s[nj][mi] = __builtin_amdgcn_mfma_f32_16x16x32_bf16(kf[nj], qf[mi], s[nj][mi], 0, 0, 0);
        __builtin_amdgcn_s_setprio(0);
        // ---- defer-max: lane-local 16-max per mi (v_max3-friendly nesting) ----
        float lm[2];
        #pragma unroll
        for (int mi = 0; mi < 2; ++mi) {
            float mx = fmaxf(s[0][mi][0], s[0][mi][1]);
            mx = fmaxf(fmaxf(mx, s[0][mi][2]), s[0][mi][3]);
            mx = fmaxf(fmaxf(mx, s[1][mi][0]), s[1][mi][1]);
            mx = fmaxf(fmaxf(mx, s[1][mi][2]), s[1][mi][3]);
            mx = fmaxf(fmaxf(mx, s[2][mi][0]), s[2][mi][1]);
            mx = fmaxf(fmaxf(mx, s[2][mi][2]), s[2][mi][3]);
            mx = fmaxf(fmaxf(mx, s[3][mi][0]), s[3][mi][1]);
            mx = fmaxf(fmaxf(mx, s[3][mi][2]), s[3][mi][3]);
            lm[mi] = mx;
        }
        bool grow = (lm[0] > mr[0] + THR) || (lm[1] > mr[1] + THR);
        if (__any(grow)) {
            #pragma unroll
            for (int mi = 0; mi < 2; ++mi) {
                float nm = lm[mi];
                nm = fmaxf(nm, __shfl_xor(nm, 16));
                nm = fmaxf(nm, __shfl_xor(nm, 32));     // reduce over hk-groups (same q)
                float mnew  = fmaxf(mr[mi], nm);
                float alpha = exp2f(mr[mi] - mnew);     // keyed q = lr
                mr[mi] = mnew;
                #pragma unroll
                for (int r = 0; r < 4; ++r) {
                    float ar = __shfl(alpha, hk * 4 + r, 16);   // rekey to q = hk*4+r
                    o_acc[mi][0][r] *= ar;
                    o_acc[mi][1][r] *= ar;
                    lsum[mi][r]     *= ar;
                }
            }
        }
        // ---- P = exp2(s - mr); pack; permlane re-fragmentation ----
        uint u[2][8];
        #pragma unroll
        for (int mi = 0; mi < 2; ++mi) {
            float ps[16];
            #pragma unroll
            for (int nj = 0; nj < 4; ++nj)
                #pragma unroll
                for (int r = 0; r < 4; ++r)
                    ps[nj * 4 + r] = exp2f(s[nj][mi][r] - mr[mi]);
            #pragma unroll
            for (int j = 0; j < 8; ++j)
                asm("v_cvt_pk_bf16_f32 %0, %1, %2" : "=v"(u[mi][j]) : "v"(ps[2 * j]), "v"(ps[2 * j + 1]));
            // quads held: {hk, 4+hk, 8+hk, 12+hk}; needed: {2hk, 2hk+1, 8+2hk, 8+2hk+1}
            asm("v_permlane32_swap_b32 %0, %1" : "+v"(u[mi][0]), "+v"(u[mi][2]));
            asm("v_permlane32_swap_b32 %0, %1" : "+v"(u[mi][1]), "+v"(u[mi][3]));
            asm("v_permlane16_swap_b32 %0, %1" : "+v"(u[mi][0]), "+v"(u[mi][2]));
            asm("v_permlane16_swap_b32 %0, %1" : "+v"(u[mi][1]), "+v"(u[mi][3]));
            asm("v_permlane32_swap_b32 %0, %1" : "+v"(u[mi][4]), "+v"(u[mi][6]));
            asm("v_permlane32_swap_b32 %0, %1" : "+v"(u[mi][5]), "+v"(u[mi][7]));
            asm("v_permlane16_swap_b32 %0, %1" : "+v"(u[mi][4]), "+v"(u[mi][6]));
            asm("v_permlane16_swap_b32 %0, %1" : "+v"(u[mi][5]), "+v"(u[mi][7]));
        }
        // ---- O += P V ;  lsum += P 1 ----
        __builtin_amdgcn_s_setprio(1);
        #pragma unroll
        for (int kq = 0; kq < 2; ++kq) {
            #pragma unroll
            for (int mi = 0; mi < 2; ++mi) {
                union { uint4 i; bf16x8 b; } pu;
                pu.i = make_uint4(u[mi][kq * 4 + 0], u[mi][kq * 4 + 1],
                                  u[mi][kq * 4 + 2], u[mi][kq * 4 + 3]);
                lsum[mi] = __builtin_amdgcn_mfma_f32_16x16x32_bf16(pu.b, ones, lsum[mi], 0, 0, 0);
                #pragma unroll
                for (int nf = 0; nf < 2; ++nf)
                    o_acc[mi][nf] = __builtin_amdgcn_mfma_f32_16x16x32_bf16(pu.b, vf[kq][nf], o_acc[mi][nf], 0, 0, 0);
            }
        }
        __builtin_amdgcn_s_setprio(0);
    }

    // ---- epilogue: lsum already in o_acc layout ----
    #pragma unroll
    for (int mi = 0; mi < 2; ++mi) {
        float inv[4];
        #pragma unroll
        for (int r = 0; r < 4; ++r) inv[r] = 1.f / lsum[mi][r];
        #pragma unroll
        for (int nf = 0; nf < 2; ++nf)
            #pragma unroll
            for (int r = 0; r < 4; ++r)
                outp[(rowbase + p0 + mi * 16 + hk * 4 + r) * 256 + hn * 32 + nf * 16 + lr] =
                    f2bf(o_acc[mi][nf][r] * inv[r]);
    }
}

// ---------------------------------------------------------------------------
extern "C" void kernel_launch(void* const* d_in, const int* in_sizes, int n_in,
                              void* d_out, int out_size, void* d_ws, size_t ws_size,
                              hipStream_t stream)
{
    const float* x   = (const float*)d_in[0];
    const float* tcw = (const float*)d_in[1];
    const float* tcb = (const float*)d_in[2];
    const float* qw  = (const float*)d_in[3];
    const float* qb  = (const float*)d_in[4];
    const float* kw  = (const float*)d_in[5];
    const float* kb  = (const float*)d_in[6];
    const float* vw  = (const float*)d_in[7];
    const float* vb  = (const float*)d_in[8];
    const float* ow  = (const float*)d_in[9];
    const float* ob  = (const float*)d_in[10];
    const float* pos = (const float*)d_in[11];

    char* ws = (char*)d_ws;
    size_t off = 0;
    auto alloc = [&](size_t bytes) {
        void* p = ws + off;
        off += (bytes + 255) & ~(size_t)255;
        return p;
    };
    ushort* xpt   = (ushort*)alloc(16384ull * 256 * 2);        // x^T + pos
    ushort* xet   = (ushort*)alloc(18432ull * 256 * 2);        // x^T zero-padded
    ushort* qkhd  = (ushort*)alloc(2ull * 8 * 16384 * 32 * 2); // Q,K per-head dense
    ushort* vbuf  = (ushort*)alloc(256ull * 16384 * 2);        // V channel-major
    ushort* attnb = (ushort*)alloc(16384ull * 256 * 2);        // attention out^T
    ushort* wqkv  = (ushort*)alloc(768ull * 256 * 2);
    ushort* wfin  = (ushort*)alloc(256ull * 1024 * 2);         // [wo | wconv]
    float*  bqkv  = (float*)alloc(768 * 4);
    float*  bfin  = (float*)alloc(256 * 4);

    prep_misc<<<2052, 256, 0, stream>>>(qw, kw, vw, ow, tcw, qb, kb, vb, ob, tcb,
                                        wqkv, wfin, bqkv, bfin,
                                        (uint4*)xet, (uint4*)(xet + 17408ull * 256));
    prep_x<<<dim3(256, 4), 256, 0, stream>>>(x, pos, xpt, xet);

    // fused Q,K,V projection (M=768): Q(scaled),K -> qkhd; V -> vbuf
    gemm_bt<0><<<dim3(256, 6), 256, 0, stream>>>(wqkv, xpt, nullptr, qkhd, vbuf, bqkv,
                                                 768, 16384, 256);

    attn_kernel<<<dim3(128, 8), 256, 0, stream>>>(qkhd, vbuf, attnb);

    // fused final: o-proj (attnb) + temporal conv (xet) + ob + tcb -> d_out f32
    gemm_bt<3><<<dim3(256, 2), 256, 0, stream>>>(wfin, attnb, xet, (float*)d_out, nullptr, bfin,
                                                 256, 16384, 1024);
}

// Round 7
// 111.787 us; speedup vs baseline: 1.3904x; 1.0014x over previous
//
#include <hip/hip_runtime.h>
#include <hip/hip_bf16.h>

// ---------------------------------------------------------------------------
// DiffusionMemory: temporal conv (3,1,1) + per-frame spatial attention + projs
// C=256, T=16, H*W=1024, heads=8, hd=32.  All matmuls via mfma_f32_16x16x32_bf16.
// Attention: swapped QK^T -> P lane-local; re-fragmentation via cvt_pk+permlane
// (zero LDS).  Softmax scale folded into Q at projection time.
// Final GEMM fuses o-proj (K=256 on attnb) + temporal conv (K=768 on xet).
// ---------------------------------------------------------------------------

typedef __bf16 bf16x8 __attribute__((ext_vector_type(8)));
typedef float  f32x4  __attribute__((ext_vector_type(4)));

__device__ __forceinline__ ushort f2bf(float f) {
    union { float f; unsigned int u; } x; x.f = f;
    unsigned int r = x.u + 0x7FFFu + ((x.u >> 16) & 1u);   // RNE
    return (ushort)(r >> 16);
}

__device__ __forceinline__ bf16x8 ldg8(const ushort* p) {
    union { int4 i; bf16x8 b; } u;
    u.i = *reinterpret_cast<const int4*>(p);
    return u.b;
}

#define SCL_QK 0.25504600765996234f   // hd^-0.5 * log2(e)

// ---------------- misc prep: pad zeroing + weight repack (one launch) --------
// wqkv [768][256] (Q,K,V rows; Q rows pre-scaled later in GEMM epilogue),
// wfin [256][1024] = [wo | wconv(col=256+kseg*256+c)], bqkv[768], bfin[256]=ob+tcb
__global__ void prep_misc(const float* __restrict__ qw, const float* __restrict__ kw,
                          const float* __restrict__ vw, const float* __restrict__ ow,
                          const float* __restrict__ tcw,
                          const float* __restrict__ qb, const float* __restrict__ kb,
                          const float* __restrict__ vb, const float* __restrict__ ob,
                          const float* __restrict__ tcb,
                          ushort* __restrict__ wqkv, ushort* __restrict__ wfin,
                          float* __restrict__ bqkv, float* __restrict__ bfin,
                          uint4* __restrict__ pad0, uint4* __restrict__ pad1)
{
    int i = blockIdx.x * 256 + threadIdx.x;
    if (i < 65536) {                         // zero xet padding frames
        if (i < 32768) pad0[i] = make_uint4(0u,0u,0u,0u);
        else           pad1[i - 32768] = make_uint4(0u,0u,0u,0u);
        return;
    }
    int j = i - 65536;
    if (j < 196608) {                        // wqkv
        int m = j >> 8, k = j & 255;
        float val = (m < 256) ? qw[m * 256 + k]
                  : (m < 512) ? kw[(m - 256) * 256 + k]
                              : vw[(m - 512) * 256 + k];
        wqkv[j] = f2bf(val);
    } else if (j < 458752) {                 // wfin [256][1024]
        int p = j - 196608;
        int o = p >> 10, col = p & 1023;
        float val;
        if (col < 256) val = ow[o * 256 + col];
        else { int q = col - 256; int c = q & 255, kseg = q >> 8;
               val = tcw[o * 768 + c * 3 + kseg]; }
        wfin[p] = f2bf(val);
    } else if (j < 459520) {                 // bqkv
        int b = j - 458752;
        bqkv[b] = (b < 256) ? qb[b] : (b < 512) ? kb[b - 256] : vb[b - 512];
    } else if (j < 459776) {                 // bfin = ob + tcb
        int b = j - 459520;
        bfin[b] = ob[b] + tcb[b];
    }
}

// ---------------- x transpose ----------------
__global__ __launch_bounds__(256)
void prep_x(const float* __restrict__ x, const float* __restrict__ pos,
            ushort* __restrict__ xpt, ushort* __restrict__ xet)
{
    __shared__ float tile[64][65];
    const int tp0 = blockIdx.x * 64;
    const int c0  = blockIdx.y * 64;
    const int tid = threadIdx.x;

    {
        const int j = tid & 63, i0 = (tid >> 6) * 16;
        #pragma unroll
        for (int rr = 0; rr < 16; ++rr) {
            int i = i0 + rr;
            tile[i][j] = x[(size_t)(c0 + i) * 16384 + tp0 + j];
        }
    }
    __syncthreads();
    {
        const int ii = tid & 63, jj0 = (tid >> 6) * 16;
        #pragma unroll
        for (int rr = 0; rr < 16; ++rr) {
            int jj = jj0 + rr;
            float val = tile[ii][jj];
            int c = c0 + ii, tp = tp0 + jj;
            int t = tp >> 10;
            xpt[(size_t)tp * 256 + c] = f2bf(val + pos[c * 16 + t]);
            xet[(size_t)(tp + 1024) * 256 + c] = f2bf(val);
        }
    }
}

// ---------------- GEMM:  C[m][n] = sum_k A[m][k] * B'[.,k%256] ----------------
// MODE 0: QKV projection, K=256. rows<256: Q (scaled by SCL_QK) -> qkhd;
//         rows<512: K -> qkhd; rows>=512: V channel-major -> outp2.
// MODE 3: fused final, K=1024. seg0: B=attnb rows n; seg1-3: B2=xet rows
//         n+(seg-1)*1024.  f32 out + bias (= ob+tcb).
template<int MODE>
__global__ __launch_bounds__(256)
void gemm_bt(const ushort* __restrict__ A, const ushort* __restrict__ B,
             const ushort* __restrict__ B2,
             void* __restrict__ outp, void* __restrict__ outp2,
             const float* __restrict__ bias,
             const int M, const int N, const int K)
{
    __shared__ __align__(16) ushort As[128][72];
    __shared__ __align__(16) ushort Bs[64][72];

    const int tid  = threadIdx.x;
    const int lane = tid & 63;
    const int w    = tid >> 6;
    const int lr   = lane & 15;
    const int hk   = lane >> 4;

    const int n0 = blockIdx.x * 64;
    const int m0 = blockIdx.y * 128;
    const int wm = w * 32;

    const int srow = tid >> 3;
    const int scol = (tid & 7) * 8;

    f32x4 acc[2][4] = {};

    for (int kk0 = 0; kk0 < K; kk0 += 64) {
        const int seg  = kk0 >> 8;
        const int bcol = kk0 & 255;
        const ushort* bs;
        if constexpr (MODE == 3)
            bs = (seg == 0) ? B : B2 + ((size_t)(seg - 1) << 18);   // +(seg-1)*1024*256
        else
            bs = B;
        __syncthreads();
        #pragma unroll
        for (int q = 0; q < 4; ++q) {
            const int row = srow + q * 32;
            *reinterpret_cast<int4*>(&As[row][scol]) =
                *reinterpret_cast<const int4*>(A + (size_t)(m0 + row) * K + kk0 + scol);
        }
        #pragma unroll
        for (int q = 0; q < 2; ++q) {
            const int row = srow + q * 32;
            *reinterpret_cast<int4*>(&Bs[row][scol]) =
                *reinterpret_cast<const int4*>(bs + (size_t)(n0 + row) * 256 + bcol + scol);
        }
        __syncthreads();
        #pragma unroll
        for (int ks = 0; ks < 2; ++ks) {
            bf16x8 af[2], bfr[4];
            #pragma unroll
            for (int mi = 0; mi < 2; ++mi)
                af[mi] = *reinterpret_cast<const bf16x8*>(&As[wm + mi * 16 + lr][ks * 32 + hk * 8]);
            #pragma unroll
            for (int nj = 0; nj < 4; ++nj)
                bfr[nj] = *reinterpret_cast<const bf16x8*>(&Bs[nj * 16 + lr][ks * 32 + hk * 8]);
            #pragma unroll
            for (int mi = 0; mi < 2; ++mi)
                #pragma unroll
                for (int nj = 0; nj < 4; ++nj)
                    acc[mi][nj] = __builtin_amdgcn_mfma_f32_16x16x32_bf16(af[mi], bfr[nj], acc[mi][nj], 0, 0, 0);
        }
    }

    #pragma unroll
    for (int mi = 0; mi < 2; ++mi) {
        const int mb = m0 + wm + mi * 16 + hk * 4;
        const float b0 = bias[mb + 0], b1 = bias[mb + 1], b2 = bias[mb + 2], b3 = bias[mb + 3];
        #pragma unroll
        for (int nj = 0; nj < 4; ++nj) {
            const int n = n0 + nj * 16 + lr;
            const f32x4 a = acc[mi][nj];
            if constexpr (MODE == 0) {
                if (mb < 512) {                  // Q (scaled), K -> per-head dense
                    const float sc = (mb < 256) ? SCL_QK : 1.0f;
                    ushort4 pk;
                    pk.x = f2bf((a[0] + b0) * sc); pk.y = f2bf((a[1] + b1) * sc);
                    pk.z = f2bf((a[2] + b2) * sc); pk.w = f2bf((a[3] + b3) * sc);
                    ushort* o = (ushort*)outp;
                    size_t base = (size_t)(mb >> 8) * (8ull * 16384 * 32)
                                + (size_t)((mb >> 5) & 7) * (16384ull * 32)
                                + (mb & 31);
                    *reinterpret_cast<ushort4*>(o + base + (size_t)n * 32) = pk;
                } else {                         // V -> channel-major
                    int c = mb - 512;
                    ushort* o = (ushort*)outp2;
                    o[(size_t)(c + 0) * 16384 + n] = f2bf(a[0] + b0);
                    o[(size_t)(c + 1) * 16384 + n] = f2bf(a[1] + b1);
                    o[(size_t)(c + 2) * 16384 + n] = f2bf(a[2] + b2);
                    o[(size_t)(c + 3) * 16384 + n] = f2bf(a[3] + b3);
                }
            } else {
                float* o = (float*)outp;
                o[(size_t)(mb + 0) * N + n] = a[0] + b0;
                o[(size_t)(mb + 1) * N + n] = a[1] + b1;
                o[(size_t)(mb + 2) * N + n] = a[2] + b2;
                o[(size_t)(mb + 3) * N + n] = a[3] + b3;
            }
        }
    }
}

// ---------------- flash attention, zero-LDS (swapped QK^T + permlane) --------
// qhd: [2(q,k)][8 heads][16384 tp][32 ch] bf16 (Q pre-scaled by SCL_QK)
// v  : [256][16384] bf16 (channel-major)
// out: [16384][256] bf16
__global__ __launch_bounds__(256)
void attn_kernel(const ushort* __restrict__ qhd, const ushort* __restrict__ v,
                 ushort* __restrict__ outp)
{
    const int lane = threadIdx.x & 63;
    const int w    = threadIdx.x >> 6;
    const int lr   = lane & 15;
    const int hk   = lane >> 4;

    const int prob = blockIdx.x;        // 0..127  (head*16 + t)
    const int qb   = blockIdx.y;        // 0..7
    const int hn   = prob >> 4, t = prob & 15;

    const ushort* qh = qhd + (size_t)hn * (16384 * 32);
    const ushort* kh = qhd + 8ull * 16384 * 32 + (size_t)hn * (16384 * 32);

    const int p0 = qb * 128 + w * 32;
    const size_t rowbase = (size_t)t * 1024;

    // hoisted per-lane base pointers
    const ushort* kbase = kh + (rowbase + lr) * 32 + hk * 8;              // + (kv0+nj*16)*32
    const ushort* vbase = v + (size_t)(hn * 32 + lr) * 16384 + rowbase + hk * 8;  // + nf*262144 + kv0 + kq*32

    // Q fragments (B-operand of swapped QK^T)
    bf16x8 qf[2];
    #pragma unroll
    for (int mi = 0; mi < 2; ++mi)
        qf[mi] = ldg8(qh + (rowbase + p0 + mi * 16 + lr) * 32 + hk * 8);

    union { ushort s[8]; bf16x8 v; } onesu;
    #pragma unroll
    for (int j = 0; j < 8; ++j) onesu.s[j] = 0x3F80;   // bf16 1.0
    const bf16x8 ones = onesu.v;

    f32x4 o_acc[2][2] = {};
    f32x4 lsum[2] = {};              // row-sum in o_acc layout (q = hk*4+r)
    float mr[2] = {-1e30f, -1e30f};  // running max (log2 domain), q = lr

    const float THR = 3.0f;

    for (int kv0 = 0; kv0 < 1024; kv0 += 64) {
        // ---- V loads first (hide latency under QK^T + softmax) ----
        bf16x8 vf[2][2];
        #pragma unroll
        for (int kq = 0; kq < 2; ++kq)
            #pragma unroll
            for (int nf = 0; nf < 2; ++nf)
                vf[kq][nf] = ldg8(vbase + (size_t)nf * 262144 + kv0 + kq * 32);
        // ---- K loads, then MFMA cluster ----
        bf16x8 kf[4];
        #pragma unroll
        for (int nj = 0; nj < 4; ++nj)
            kf[nj] = ldg8(kbase + (size_t)(kv0 + nj * 16) * 32);
        f32x4 s[4][2] = {};
        __builtin_amdgcn_s_setprio(1);
        #pragma unroll
        for (int nj = 0; nj < 4; ++nj)
            #pragma unroll
            for (int mi = 0; mi < 2; ++mi)
                s[nj][mi] = __builtin_amdgcn_mfma_f32_16x16x32_bf16(kf[nj], qf[mi], s[nj][mi], 0, 0, 0);
        __builtin_amdgcn_s_setprio(0);
        // ---- defer-max: lane-local 16-max per mi (v_max3-friendly nesting) ----
        float lm[2];
        #pragma unroll
        for (int mi = 0; mi < 2; ++mi) {
            float mx = fmaxf(s[0][mi][0], s[0][mi][1]);
            mx = fmaxf(fmaxf(mx, s[0][mi][2]), s[0][mi][3]);
            mx = fmaxf(fmaxf(mx, s[1][mi][0]), s[1][mi][1]);
            mx = fmaxf(fmaxf(mx, s[1][mi][2]), s[1][mi][3]);
            mx = fmaxf(fmaxf(mx, s[2][mi][0]), s[2][mi][1]);
            mx = fmaxf(fmaxf(mx, s[2][mi][2]), s[2][mi][3]);
            mx = fmaxf(fmaxf(mx, s[3][mi][0]), s[3][mi][1]);
            mx = fmaxf(fmaxf(mx, s[3][mi][2]), s[3][mi][3]);
            lm[mi] = mx;
        }
        bool grow = (lm[0] > mr[0] + THR) || (lm[1] > mr[1] + THR);
        if (__any(grow)) {
            #pragma unroll
            for (int mi = 0; mi < 2; ++mi) {
                float nm = lm[mi];
                nm = fmaxf(nm, __shfl_xor(nm, 16));
                nm = fmaxf(nm, __shfl_xor(nm, 32));     // reduce over hk-groups (same q)
                float mnew  = fmaxf(mr[mi], nm);
                float alpha = exp2f(mr[mi] - mnew);     // keyed q = lr
                mr[mi] = mnew;
                #pragma unroll
                for (int r = 0; r < 4; ++r) {
                    float ar = __shfl(alpha, hk * 4 + r, 16);   // rekey to q = hk*4+r
                    o_acc[mi][0][r] *= ar;
                    o_acc[mi][1][r] *= ar;
                    lsum[mi][r]     *= ar;
                }
            }
        }
        // ---- P = exp2(s - mr); pack; permlane re-fragmentation ----
        uint u[2][8];
        #pragma unroll
        for (int mi = 0; mi < 2; ++mi) {
            float ps[16];
            #pragma unroll
            for (int nj = 0; nj < 4; ++nj)
                #pragma unroll
                for (int r = 0; r < 4; ++r)
                    ps[nj * 4 + r] = exp2f(s[nj][mi][r] - mr[mi]);
            #pragma unroll
            for (int j = 0; j < 8; ++j)
                asm("v_cvt_pk_bf16_f32 %0, %1, %2" : "=v"(u[mi][j]) : "v"(ps[2 * j]), "v"(ps[2 * j + 1]));
            // quads held: {hk, 4+hk, 8+hk, 12+hk}; needed: {2hk, 2hk+1, 8+2hk, 8+2hk+1}
            asm("v_permlane32_swap_b32 %0, %1" : "+v"(u[mi][0]), "+v"(u[mi][2]));
            asm("v_permlane32_swap_b32 %0, %1" : "+v"(u[mi][1]), "+v"(u[mi][3]));
            asm("v_permlane16_swap_b32 %0, %1" : "+v"(u[mi][0]), "+v"(u[mi][2]));
            asm("v_permlane16_swap_b32 %0, %1" : "+v"(u[mi][1]), "+v"(u[mi][3]));
            asm("v_permlane32_swap_b32 %0, %1" : "+v"(u[mi][4]), "+v"(u[mi][6]));
            asm("v_permlane32_swap_b32 %0, %1" : "+v"(u[mi][5]), "+v"(u[mi][7]));
            asm("v_permlane16_swap_b32 %0, %1" : "+v"(u[mi][4]), "+v"(u[mi][6]));
            asm("v_permlane16_swap_b32 %0, %1" : "+v"(u[mi][5]), "+v"(u[mi][7]));
        }
        // ---- O += P V ;  lsum += P 1 ----
        __builtin_amdgcn_s_setprio(1);
        #pragma unroll
        for (int kq = 0; kq < 2; ++kq) {
            #pragma unroll
            for (int mi = 0; mi < 2; ++mi) {
                union { uint4 i; bf16x8 b; } pu;
                pu.i = make_uint4(u[mi][kq * 4 + 0], u[mi][kq * 4 + 1],
                                  u[mi][kq * 4 + 2], u[mi][kq * 4 + 3]);
                lsum[mi] = __builtin_amdgcn_mfma_f32_16x16x32_bf16(pu.b, ones, lsum[mi], 0, 0, 0);
                #pragma unroll
                for (int nf = 0; nf < 2; ++nf)
                    o_acc[mi][nf] = __builtin_amdgcn_mfma_f32_16x16x32_bf16(pu.b, vf[kq][nf], o_acc[mi][nf], 0, 0, 0);
            }
        }
        __builtin_amdgcn_s_setprio(0);
    }

    // ---- epilogue: lsum already in o_acc layout ----
    #pragma unroll
    for (int mi = 0; mi < 2; ++mi) {
        float inv[4];
        #pragma unroll
        for (int r = 0; r < 4; ++r) inv[r] = 1.f / lsum[mi][r];
        #pragma unroll
        for (int nf = 0; nf < 2; ++nf)
            #pragma unroll
            for (int r = 0; r < 4; ++r)
                outp[(rowbase + p0 + mi * 16 + hk * 4 + r) * 256 + hn * 32 + nf * 16 + lr] =
                    f2bf(o_acc[mi][nf][r] * inv[r]);
    }
}

// ---------------------------------------------------------------------------
extern "C" void kernel_launch(void* const* d_in, const int* in_sizes, int n_in,
                              void* d_out, int out_size, void* d_ws, size_t ws_size,
                              hipStream_t stream)
{
    const float* x   = (const float*)d_in[0];
    const float* tcw = (const float*)d_in[1];
    const float* tcb = (const float*)d_in[2];
    const float* qw  = (const float*)d_in[3];
    const float* qb  = (const float*)d_in[4];
    const float* kw  = (const float*)d_in[5];
    const float* kb  = (const float*)d_in[6];
    const float* vw  = (const float*)d_in[7];
    const float* vb  = (const float*)d_in[8];
    const float* ow  = (const float*)d_in[9];
    const float* ob  = (const float*)d_in[10];
    const float* pos = (const float*)d_in[11];

    char* ws = (char*)d_ws;
    size_t off = 0;
    auto alloc = [&](size_t bytes) {
        void* p = ws + off;
        off += (bytes + 255) & ~(size_t)255;
        return p;
    };
    ushort* xpt   = (ushort*)alloc(16384ull * 256 * 2);        // x^T + pos
    ushort* xet   = (ushort*)alloc(18432ull * 256 * 2);        // x^T zero-padded
    ushort* qkhd  = (ushort*)alloc(2ull * 8 * 16384 * 32 * 2); // Q,K per-head dense
    ushort* vbuf  = (ushort*)alloc(256ull * 16384 * 2);        // V channel-major
    ushort* attnb = (ushort*)alloc(16384ull * 256 * 2);        // attention out^T
    ushort* wqkv  = (ushort*)alloc(768ull * 256 * 2);
    ushort* wfin  = (ushort*)alloc(256ull * 1024 * 2);         // [wo | wconv]
    float*  bqkv  = (float*)alloc(768 * 4);
    float*  bfin  = (float*)alloc(256 * 4);

    prep_misc<<<2052, 256, 0, stream>>>(qw, kw, vw, ow, tcw, qb, kb, vb, ob, tcb,
                                        wqkv, wfin, bqkv, bfin,
                                        (uint4*)xet, (uint4*)(xet + 17408ull * 256));
    prep_x<<<dim3(256, 4), 256, 0, stream>>>(x, pos, xpt, xet);

    // fused Q,K,V projection (M=768): Q(scaled),K -> qkhd; V -> vbuf
    gemm_bt<0><<<dim3(256, 6), 256, 0, stream>>>(wqkv, xpt, nullptr, qkhd, vbuf, bqkv,
                                                 768, 16384, 256);

    attn_kernel<<<dim3(128, 8), 256, 0, stream>>>(qkhd, vbuf, attnb);

    // fused final: o-proj (attnb) + temporal conv (xet) + ob + tcb -> d_out f32
    gemm_bt<3><<<dim3(256, 2), 256, 0, stream>>>(wfin, attnb, xet, (float*)d_out, nullptr, bfin,
                                                 256, 16384, 1024);
}